// Round 13
// baseline (274.924 us; speedup 1.0000x reference)
//
#include <hip/hip_runtime.h>

// GCN 3-layer, R22 == R21 resubmitted verbatim (R21's bench run died with a
// container-infrastructure error before compiling/verifying anything — no
// information gained; predictions stand).
//  - R20 result: single-drain gather + split dot = 65.7us (-5%). VALUBusy
//    still 43%, occ 33%. Cycle audit: VALU floor ~23us/SIMD (readlane dot =
//    256 cy/node dominates); measured VALU time 0.43*66 ~ 28us. Remaining
//    ~38us = un-overlapped gather latency: every design so far ALTERNATES
//    {drain gather -> serial dot}, idling VALU during waits and memory
//    during dots, with only ~2.6 resident waves. That alternation is the
//    shared ~66-69us invariant.
//  - R21/R22: process node pairs. Issue BOTH nodes' gathers back-to-back
//    (16 eager edges each + self), then node0's sum+dot (compiler's counted
//    vmcnt leaves node1's loads outstanding), then node1's. Node1's ~500cy
//    latency hides under node0's ~400cy dot.
//  - Eager window 32->16 edges (covers deg<=16, ~97%; uniform scalar tail
//    for deg>16) keeps VGPR ~116 < 128 cap (wc64 + 2x16 u16 + misc).
//  - Per-node FP order unchanged from R20 (e-ascending, tail, self; 4-chain
//    dot). Threshold 2.9e-3 >> any reassociation here.
//  - Predict: PASS 4.882812e-04; k_fgt64 -> 45-55us, VALUBusy 55-65%,
//    VGPR 110-120; total -> 252-262us.
//    Flat@66 -> alternation theory wrong; L3 random-access floor ->
//    roofline or kernel-split next.

#define CAP 32
#define BSH 7                 // 128 nodes per bucket
#define BW 128
#define BCAP 1664             // slots/bucket: mean 1279 + 10.7 sigma
#define EPT 4                 // edges per thread in k_part (R16-verified)

typedef unsigned short u16;
typedef unsigned int u32;

__device__ __forceinline__ float bf2f(u16 u) {
    return __uint_as_float(((u32)u) << 16);
}
__device__ __forceinline__ u16 f2bf(float f) {
    u32 x = __float_as_uint(f);
    u32 r = x + 0x7fff + ((x >> 16) & 1);  // round-to-nearest-even
    return (u16)(r >> 16);
}
__device__ __forceinline__ float fast_tanh(float x) {
    x = fminf(15.f, fmaxf(-15.f, x));
    float e = __expf(2.f * x);
    return (e - 1.f) / (e + 1.f);
}
__device__ __forceinline__ int unpack_deg(const u32* pk, int n) {
    return (int)((pk[n >> 2] >> (8 * (n & 3))) & 255u);
}

// ---- cursor init ----
__global__ __launch_bounds__(256) void k_init(int* __restrict__ curR,
                                              int* __restrict__ curS, int nbuk) {
    int t = blockIdx.x * 256 + threadIdx.x;
    if (t < nbuk) {
        curR[t] = t * BCAP;
        curS[t] = t * BCAP;
    }
}

// ---- two-phase binned partition: (s,r) by r-bucket, s by s-bucket ----
__global__ __launch_bounds__(1024) void k_part(const int* __restrict__ s,
                                               const int* __restrict__ r,
                                               int* __restrict__ curR,
                                               int* __restrict__ curS,
                                               int2* __restrict__ pairR,
                                               int* __restrict__ svalS,
                                               int E, int nbuk) {
    __shared__ int cR[1024], cS[1024], bR[1024], bS[1024];
    const int t = threadIdx.x;
    for (int i = t; i < nbuk; i += 1024) { cR[i] = 0; cS[i] = 0; }
    __syncthreads();

    int ss[EPT], rr[EPT];
    const int base = blockIdx.x * (1024 * EPT);
#pragma unroll
    for (int i = 0; i < EPT; ++i) {
        int e = base + i * 1024 + t;       // coalesced per i-step
        ss[i] = (e < E) ? s[e] : -1;
        rr[i] = (e < E) ? r[e] : -1;
    }
#pragma unroll
    for (int i = 0; i < EPT; ++i) {
        if (rr[i] >= 0) {
            atomicAdd(&cR[rr[i] >> BSH], 1);
            atomicAdd(&cS[ss[i] >> BSH], 1);
        }
    }
    __syncthreads();
    // one global reservation per (block,bucket)
    for (int i = t; i < nbuk; i += 1024) {
        bR[i] = cR[i] ? atomicAdd(&curR[i], cR[i]) : 0;
        bS[i] = cS[i] ? atomicAdd(&curS[i], cS[i]) : 0;
    }
    __syncthreads();
    for (int i = t; i < nbuk; i += 1024) { cR[i] = 0; cS[i] = 0; }
    __syncthreads();
#pragma unroll
    for (int i = 0; i < EPT; ++i) {
        if (rr[i] >= 0) {
            int rb = rr[i] >> BSH;
            int pos = bR[rb] + atomicAdd(&cR[rb], 1);
            if (pos < (rb + 1) * BCAP) pairR[pos] = make_int2(ss[i], rr[i]);
            int sb = ss[i] >> BSH;
            int ps = bS[sb] + atomicAdd(&cS[sb], 1);
            if (ps < (sb + 1) * BCAP) svalS[ps] = ss[i];
        }
    }
}

// ---- per-bucket ELL build + packed in-degree bytes (LDS counters only) ----
__global__ __launch_bounds__(256) void k_ellb(const int2* __restrict__ pairR,
                                              const int* __restrict__ curR,
                                              int* __restrict__ ell,
                                              u32* __restrict__ degIp) {
    __shared__ int degLoc[BW];
    const int b = blockIdx.x, t = threadIdx.x;
    if (t < BW) degLoc[t] = 0;
    __syncthreads();
    const int start = b * BCAP;
    const int cnt = min(curR[b] - start, BCAP);
    for (int e = t; e < cnt; e += 256) {
        int2 p = pairR[start + e];
        int slot = atomicAdd(&degLoc[p.y - (b << BSH)], 1);
        if (slot < CAP) ell[p.y * CAP + slot] = p.x;
    }
    __syncthreads();
    if (t < BW / 4) {
        u32 w = (u32)min(degLoc[4 * t], 255) |
                ((u32)min(degLoc[4 * t + 1], 255) << 8) |
                ((u32)min(degLoc[4 * t + 2], 255) << 16) |
                ((u32)min(degLoc[4 * t + 3], 255) << 24);
        degIp[(b << (BSH - 2)) + t] = w;
    }
}

// ---- per-bucket out-degree histogram (packed bytes) ----
__global__ __launch_bounds__(256) void k_dego(const int* __restrict__ svalS,
                                              const int* __restrict__ curS,
                                              u32* __restrict__ degOp) {
    __shared__ int degLoc[BW];
    const int b = blockIdx.x, t = threadIdx.x;
    if (t < BW) degLoc[t] = 0;
    __syncthreads();
    const int start = b * BCAP;
    const int cnt = min(curS[b] - start, BCAP);
    for (int e = t; e < cnt; e += 256) {
        atomicAdd(&degLoc[svalS[start + e] - (b << BSH)], 1);
    }
    __syncthreads();
    if (t < BW / 4) {
        u32 w = (u32)min(degLoc[4 * t], 255) |
                ((u32)min(degLoc[4 * t + 1], 255) << 8) |
                ((u32)min(degLoc[4 * t + 2], 255) << 16) |
                ((u32)min(degLoc[4 * t + 3], 255) << 24);
        degOp[(b << (BSH - 2)) + t] = w;
    }
}

// ---- layer-0 dense 64x64 transform: f32 in, bf16 out ---- (R16-exact)
__global__ __launch_bounds__(256, 4) void k_transform64(const float* __restrict__ in,
                                                        const float* __restrict__ W,
                                                        const float* __restrict__ b,
                                                        const u32* __restrict__ degOp,
                                                        u16* __restrict__ out, int N) {
    __shared__ float4 lds[4][128]; // 8 rows x 16 float4 per wave
    const int lane = threadIdx.x & 63;
    const int wv = threadIdx.x >> 6;

    float wc[64];
#pragma unroll
    for (int k = 0; k < 64; ++k) wc[k] = W[k * 64 + lane];
    const float bias = b[lane];

    const int base = blockIdx.x * 32 + wv * 8;
    const float4* in4 = (const float4*)in;
#pragma unroll
    for (int r2 = 0; r2 < 2; ++r2) {
        int idx = r2 * 64 + lane;
        int nn = base + (idx >> 4);
        float4 v = {0.f, 0.f, 0.f, 0.f};
        if (nn < N) v = in4[(size_t)base * 16 + idx];
        lds[wv][idx] = v;
    }
#pragma unroll
    for (int i = 0; i < 8; ++i) {
        const int n = base + i;
        if (n >= N) break;
        float acc = 0.f;
#pragma unroll
        for (int kk = 0; kk < 16; ++kk) {
            float4 h = lds[wv][i * 16 + kk];
            acc = fmaf(h.x, wc[4 * kk + 0], acc);
            acc = fmaf(h.y, wc[4 * kk + 1], acc);
            acc = fmaf(h.z, wc[4 * kk + 2], acc);
            acc = fmaf(h.w, wc[4 * kk + 3], acc);
        }
        float as01 = rsqrtf((float)unpack_deg(degOp, n) + 1.f);
        acc = fast_tanh(acc + bias) * as01;
        out[(size_t)n * 64 + lane] = f2bf(acc);
    }
}

// ---- helper: sum + dot + store for one node (feature-per-lane) ----
__device__ __forceinline__ void fgt64_finish(const u16* __restrict__ h,
                                             const float* wc, float bias,
                                             const u16* a, u16 aself,
                                             const int* __restrict__ rowp,
                                             int deg, int di, int dego,
                                             u16* __restrict__ y, int n, int lane) {
    // sum eager window (e-ascending; +0 exact for dead slots)
    float acc = 0.f;
#pragma unroll
    for (int e = 0; e < 16; ++e) acc += (e < deg) ? bf2f(a[e]) : 0.f;
    // rare tail (deg>16, ~3% of nodes): uniform scalar loop
    for (int e = 16; e < deg; ++e) {
        int id = rowp[e];
        acc += bf2f(h[(size_t)id * 64 + lane]);
    }
    // self edge
    acc += bf2f(aself);

    const float inscale = rsqrtf((float)di + 1.f);            // ar01
    const float outscale = rsqrtf((float)dego + 1.f);         // as01

    // dot(row, wc): row[k] lives in lane k. 4 independent chains.
    float d0 = 0.f, d1 = 0.f, d2 = 0.f, d3 = 0.f;
#pragma unroll
    for (int k = 0; k < 16; ++k) {
        d0 = fmaf(__uint_as_float(__builtin_amdgcn_readlane(
                 __float_as_uint(acc), k)),      wc[k],      d0);
        d1 = fmaf(__uint_as_float(__builtin_amdgcn_readlane(
                 __float_as_uint(acc), k + 16)), wc[k + 16], d1);
        d2 = fmaf(__uint_as_float(__builtin_amdgcn_readlane(
                 __float_as_uint(acc), k + 32)), wc[k + 32], d2);
        d3 = fmaf(__uint_as_float(__builtin_amdgcn_readlane(
                 __float_as_uint(acc), k + 48)), wc[k + 48], d3);
    }
    float dot = (d0 + d1) + (d2 + d3);
    float v = fast_tanh(fmaf(dot, inscale, bias)) * outscale;
    y[(size_t)n * 64 + lane] = f2bf(v);
}

// ---- fused gather + 64x64 transform (layer 1): two-node pipeline ----
// Feature-per-lane, scalar-uniform control (R19/R20-verified base).
// Node pairs: issue BOTH nodes' 16-edge eager gathers + self rows
// back-to-back, then finish node0 (counted vmcnt leaves node1's loads
// in flight), then node1. No LDS, no cross-lane memory.
__global__ __launch_bounds__(256, 4) void k_fgt64(const u16* __restrict__ h,
                                                  const u32* __restrict__ degOp,
                                                  const u32* __restrict__ degIp,
                                                  const int* __restrict__ ell,
                                                  const float* __restrict__ W,
                                                  const float* __restrict__ b,
                                                  u16* __restrict__ y, int N) {
    const int lane = threadIdx.x & 63;
    const int wv = __builtin_amdgcn_readfirstlane(threadIdx.x >> 6); // uniform

    float wc[64];   // W1 column for output feature `lane`
#pragma unroll
    for (int k = 0; k < 64; ++k) wc[k] = W[k * 64 + lane];
    const float bias = b[lane];

    const int base = blockIdx.x * 32 + wv * 8;   // uniform
#pragma unroll
    for (int p = 0; p < 4; ++p) {
        const int n0 = base + 2 * p;             // uniform
        if (n0 >= N) break;
        const int n1 = n0 + 1;
        const bool has1 = (n1 < N);              // uniform

        const int di0 = unpack_deg(degIp, n0);
        const int deg0 = min(di0, CAP);
        const int* __restrict__ rowp0 = ell + (size_t)n0 * CAP;
        const int dego0 = unpack_deg(degOp, n0);

        int di1 = 0, deg1 = 0, dego1 = 0;
        const int* __restrict__ rowp1 = ell + (size_t)n1 * CAP;
        if (has1) {
            di1 = unpack_deg(degIp, n1);
            deg1 = min(di1, CAP);
            dego1 = unpack_deg(degOp, n1);
        }

        // ---- issue ALL loads for both nodes back-to-back ----
        u16 aself0 = h[(size_t)n0 * 64 + lane];
        u16 a0[16];
#pragma unroll
        for (int e = 0; e < 16; ++e) {
            int id = (e < deg0) ? rowp0[e] : n0;   // clamp: safe + L1-hot
            a0[e] = h[(size_t)id * 64 + lane];
        }
        u16 aself1 = aself0;
        u16 a1[16];
        if (has1) {
            aself1 = h[(size_t)n1 * 64 + lane];
#pragma unroll
            for (int e = 0; e < 16; ++e) {
                int id = (e < deg1) ? rowp1[e] : n1;
                a1[e] = h[(size_t)id * 64 + lane];
            }
        }

        // ---- finish node0 (node1's loads stay outstanding) ----
        fgt64_finish(h, wc, bias, a0, aself0, rowp0, deg0, di0, dego0, y, n0, lane);
        // ---- finish node1 ----
        if (has1)
            fgt64_finish(h, wc, bias, a1, aself1, rowp1, deg1, di1, dego1, y, n1, lane);
    }
}

// ---- fused gather + 64->16 transform (layer 2): 8 nodes per wave, bf16 ----
// R16-exact text (known-good schedule).
__global__ __launch_bounds__(256, 4) void k_fgt16(const u16* __restrict__ h,
                                                  const u32* __restrict__ degOp,
                                                  const u32* __restrict__ degIp,
                                                  const int* __restrict__ ell,
                                                  const float* __restrict__ W, // 64x16
                                                  const float* __restrict__ b,
                                                  u16* __restrict__ y16, int N) {
    __shared__ float4 lds[4][16];
    const int lane = threadIdx.x & 63;
    const int wv = threadIdx.x >> 6;
    const int g = lane >> 4, c = lane & 15;
    const int j = lane & 15;

    float wc[16]; // W2 rows [16g,16g+16) for output feature j — once per wave
#pragma unroll
    for (int kk = 0; kk < 16; ++kk) wc[kk] = W[(16 * g + kk) * 16 + j];
    const float bias = b[j];

    const ushort4* h4 = (const ushort4*)h;
    const int base = blockIdx.x * 32 + wv * 8;
    for (int i8 = 0; i8 < 8; ++i8) {
        const int n = base + i8;
        if (n >= N) break;
        const int di = unpack_deg(degIp, n);
        const int deg = min(di, CAP);
        int idxv = (lane < CAP) ? ell[n * CAP + lane] : 0;

        float4 acc = {0.f, 0.f, 0.f, 0.f};
        const int jn = (deg + 3) >> 2;
        for (int jj = 0; jj < jn; ++jj) {
            int i = g + 4 * jj;
            int id = __shfl(idxv, i, 64);
            if (i < deg) {
                ushort4 v = h4[(size_t)id * 16 + c];
                acc.x += bf2f(v.x); acc.y += bf2f(v.y);
                acc.z += bf2f(v.z); acc.w += bf2f(v.w);
            }
        }
#pragma unroll
        for (int m = 16; m <= 32; m <<= 1) {
            acc.x += __shfl_xor(acc.x, m, 64);
            acc.y += __shfl_xor(acc.y, m, 64);
            acc.z += __shfl_xor(acc.z, m, 64);
            acc.w += __shfl_xor(acc.w, m, 64);
        }
        // self edge AFTER butterfly
        ushort4 sv = h4[(size_t)n * 16 + c];
        acc.x += bf2f(sv.x); acc.y += bf2f(sv.y);
        acc.z += bf2f(sv.z); acc.w += bf2f(sv.w);
        if (g == 0) lds[wv][c] = acc;

        const float* row = (const float*)lds[wv];
        float dot = 0.f;
#pragma unroll
        for (int kk = 0; kk < 16; ++kk) dot = fmaf(row[16 * g + kk], wc[kk], dot);
#pragma unroll
        for (int m = 16; m <= 32; m <<= 1) dot += __shfl_xor(dot, m, 64);

        if (g == 0) {
            const float inscale = rsqrtf((float)di + 1.f);                          // ar01
            const float outscale = rsqrtf(fmaxf((float)unpack_deg(degOp, n), 1.f)); // as2
            float v = fmaf(dot, inscale, bias) * outscale;
            y16[(size_t)n * 16 + j] = f2bf(v);
        }
    }
}

// ---- final gather over 16 feats (no self): bf16 -> f32, scale ar2 ---- (R16-exact)
__global__ __launch_bounds__(256) void k_g16(const u16* __restrict__ h,
                                             const u32* __restrict__ degIp,
                                             const int* __restrict__ ell,
                                             float* __restrict__ out, int N) {
    const int lane = threadIdx.x & 63;
    const int wv = threadIdx.x >> 6;
    const int n = blockIdx.x * 4 + wv;
    if (n >= N) return;
    const int g = lane >> 2, c = lane & 3;   // 16 edge groups x 4 feat-lanes
    const int di = unpack_deg(degIp, n);
    const int deg = min(di, CAP);
    int idxv = (lane < CAP) ? ell[n * CAP + lane] : 0;

    const ushort4* h4 = (const ushort4*)h;   // row = 4 x ushort4 (16 bf16)
    float4 acc = {0.f, 0.f, 0.f, 0.f};
    const int jn = (deg + 15) >> 4;
    for (int j = 0; j < jn; ++j) {
        int i = g + 16 * j;
        int id = __shfl(idxv, i, 64);
        if (i < deg) {
            ushort4 v = h4[(size_t)id * 4 + c];
            acc.x += bf2f(v.x); acc.y += bf2f(v.y);
            acc.z += bf2f(v.z); acc.w += bf2f(v.w);
        }
    }
#pragma unroll
    for (int m = 4; m <= 32; m <<= 1) {
        acc.x += __shfl_xor(acc.x, m, 64);
        acc.y += __shfl_xor(acc.y, m, 64);
        acc.z += __shfl_xor(acc.z, m, 64);
        acc.w += __shfl_xor(acc.w, m, 64);
    }
    if (g == 0) {
        float sc = rsqrtf(fmaxf((float)di, 1.f));   // ar2
        acc.x *= sc; acc.y *= sc; acc.z *= sc; acc.w *= sc;
        ((float4*)out)[(size_t)n * 4 + c] = acc;
    }
}

extern "C" void kernel_launch(void* const* d_in, const int* in_sizes, int n_in,
                              void* d_out, int out_size, void* d_ws, size_t ws_size,
                              hipStream_t stream) {
    const float* nodes = (const float*)d_in[0];
    const int* senders = (const int*)d_in[1];
    const int* receivers = (const int*)d_in[2];
    const float* W0 = (const float*)d_in[3];
    const float* b0 = (const float*)d_in[4];
    const float* W1 = (const float*)d_in[5];
    const float* b1 = (const float*)d_in[6];
    const float* W2 = (const float*)d_in[7];
    const float* b2 = (const float*)d_in[8];
    float* out = (float*)d_out;

    const int N = in_sizes[0] / 64;            // 100000
    const int E = in_sizes[1];                 // 1000000
    const int nbuk = (N + BW - 1) >> BSH;      // 782
    const int nwords = nbuk * (BW / 4);        // packed degree words

    // workspace layout (~58 MB)
    u16* A = (u16*)d_ws;                         // N*64 bf16
    u16* B = A + (size_t)N * 64;                 // N*64 bf16
    u16* Y16 = B + (size_t)N * 64;               // N*16 bf16
    u32* degOp = (u32*)(Y16 + (size_t)N * 16);   // nwords
    u32* degIp = degOp + nwords;                 // nwords
    int* curR = (int*)(degIp + nwords);          // nbuk
    int* curS = curR + nbuk;                     // nbuk
    int* ell = (int*)(curS + nbuk);              // N*CAP row-major
    int2* pairR = (int2*)(ell + (size_t)N * CAP);// nbuk*BCAP int2
    int* svalS = (int*)(pairR + (size_t)nbuk * BCAP); // nbuk*BCAP

    // structure build (no global memsets, no per-edge global atomics)
    k_init<<<(nbuk + 255) / 256, 256, 0, stream>>>(curR, curS, nbuk);
    const int pblk = (E + 1024 * EPT - 1) / (1024 * EPT);  // 245
    k_part<<<pblk, 1024, 0, stream>>>(senders, receivers, curR, curS,
                                      pairR, svalS, E, nbuk);
    k_ellb<<<nbuk, 256, 0, stream>>>(pairR, curR, ell, degIp);
    k_dego<<<nbuk, 256, 0, stream>>>(svalS, curS, degOp);

    const int tb = (N + 31) / 32;
    const int fb = (N + 31) / 32;   // fused kernels: 32 nodes per block
    const int gb = (N + 3) / 4;

    // layer 0: A = bf16( tanh(nodes@W0+b0)*as01 )
    k_transform64<<<tb, 256, 0, stream>>>(nodes, W0, b0, degOp, A, N);
    // layer 1 fused: B = bf16( tanh(ar01*dot(gather(A)+A, W1)+b1)*as01 )
    k_fgt64<<<fb, 256, 0, stream>>>(A, degOp, degIp, ell, W1, b1, B, N);
    // layer 2 fused: Y16 = bf16( (ar01*dot(gather(B)+B, W2)+b2)*as2 )
    k_fgt16<<<fb, 256, 0, stream>>>(B, degOp, degIp, ell, W2, b2, Y16, N);
    // final aggregation: out = ar2 * gather16(Y16), f32
    k_g16<<<gb, 256, 0, stream>>>(Y16, degIp, ell, out, N);
}